// Round 4
// baseline (728.419 us; speedup 1.0000x reference)
//
#include <hip/hip_runtime.h>
#include <stdint.h>

typedef __attribute__((ext_vector_type(8))) __bf16 bf16x8;
typedef __attribute__((ext_vector_type(4))) float  f32x4;

// ---------- helpers ----------
__device__ __forceinline__ uint16_t f2b(float f) {           // fp32 -> bf16 RNE
  uint32_t u = __float_as_uint(f);
  u += 0x7fffu + ((u >> 16) & 1u);
  return (uint16_t)(u >> 16);
}
__device__ __forceinline__ float b2f_lo(uint32_t p) { return __uint_as_float(p << 16); }
__device__ __forceinline__ float b2f_hi(uint32_t p) { return __uint_as_float(p & 0xffff0000u); }

// hardware packed fp32->bf16 RNE (2 elems / instr); same rounding as f2b
__device__ __forceinline__ uint32_t cvtpk(float lo, float hi) {
  uint32_t r;
  asm("v_cvt_pk_bf16_f32 %0, %1, %2" : "=v"(r) : "v"(lo), "v"(hi));
  return r;
}

// branch-free tanh: 1 - 2/(e^{2x}+1); saturates correctly at +-1
__device__ __forceinline__ float tanh_fast(float x) {
  float e = __expf(2.0f * x);
  return 1.0f - 2.0f / (e + 1.0f);
}

// barrier draining ONLY lgkmcnt (ds ops) — global prefetch stays in flight.
__device__ __forceinline__ void barrier_lgkm() {
  asm volatile("s_waitcnt lgkmcnt(0)\n\ts_barrier" ::: "memory");
}

// ---------- 1. prep: W_a transpose->bf16 (blocks 0..255) + u = dec_last @ U_a
//              (blocks 256..511, atomic fp32 partials) merged into one dispatch.
__global__ __launch_bounds__(256) void prep(const float* __restrict__ W,
                                            uint16_t* __restrict__ WT,
                                            const float* __restrict__ dec,
                                            const float4* __restrict__ U4,
                                            float* __restrict__ u) {
  __shared__ float tile[64][65];
  if (blockIdx.x < 256) {
    // ---- W_a (K x N) -> WT bf16 (N x K), LDS-tiled transpose ----
    int k0 = (blockIdx.x & 15) * 64;
    int n0 = (blockIdx.x >> 4) * 64;
    #pragma unroll
    for (int it = 0; it < 16; ++it) {
      int idx = it * 256 + threadIdx.x;
      int kr = idx >> 6, nc = idx & 63;
      tile[kr][nc] = W[(size_t)(k0 + kr) * 1024 + n0 + nc];
    }
    __syncthreads();
    #pragma unroll
    for (int it = 0; it < 16; ++it) {
      int idx = it * 256 + threadIdx.x;
      int nr = idx >> 6, kc = idx & 63;
      WT[(size_t)(n0 + nr) * 1024 + k0 + kc] = f2b(tile[kc][nr]);
    }
  } else {
    // ---- u[b,f] += sum_{d in seg} dec_last[b,d] * U[d,f] ----
    int bx = blockIdx.x - 256;
    int b = bx >> 3, dseg = bx & 7;
    float* sdec = &tile[0][0];
    if (threadIdx.x < 128)
      sdec[threadIdx.x] = dec[(size_t)b * 64 * 1024 + 63 * 1024 + dseg * 128 + threadIdx.x];
    __syncthreads();
    float4 a = {0.f, 0.f, 0.f, 0.f};
    const float4* Ub = U4 + (size_t)dseg * 128 * 256 + threadIdx.x;
    #pragma unroll 4
    for (int d = 0; d < 128; ++d) {
      float4 w = Ub[(size_t)d * 256];
      float s = sdec[d];
      a.x = fmaf(s, w.x, a.x);
      a.y = fmaf(s, w.y, a.y);
      a.z = fmaf(s, w.z, a.z);
      a.w = fmaf(s, w.w, a.w);
    }
    float* up = u + b * 1024 + threadIdx.x * 4;
    atomicAdd(up + 0, a.x);
    atomicAdd(up + 1, a.y);
    atomicAdd(up + 2, a.z);
    atomicAdd(up + 3, a.w);
  }
}

// ---------- 2. fused GEMM (R0 structure) reading fp32 A with in-reg bf16 convert
// spart[ntile][r] = sum_{f in ntile} v[f]*tanh((A@W)[r,f]+u[b,f])
// 128x128 tile, 4 waves, BK=32, LDS double-buffer, lgkm-only barrier, named
// prefetch regs, XOR-swizzled fragment-order LDS slots (proven: 0 conflicts).
// NEW: A loaded as fp32 (2x float4 per 16B-bf16 chunk), packed via
// v_cvt_pk_bf16_f32 at ds_write time -> convert_enc kernel deleted.
// ntile==0 blocks additionally export the converted tile to encA (write hidden
// under compute; keeps context_k's read at 128 MB bf16).
__global__ __launch_bounds__(256, 3) void gemm_score(const float* __restrict__ Af,
                                                     const uint16_t* __restrict__ BT,
                                                     const float* __restrict__ u,
                                                     const float* __restrict__ v,
                                                     float* __restrict__ spart,
                                                     uint16_t* __restrict__ encA) {
  __shared__ uint4 sAB[2][1024];  // [buf][ A slots 0..511 | B slots 512..1023 ]
  __shared__ float sred[128];

  int bx = blockIdx.x;
  int g = bx >> 6, r = bx & 63;
  int mtile = g * 8 + (r & 7);
  int ntile = r >> 3;

  int tid = threadIdx.x;
  int lane = tid & 63;
  int wid  = tid >> 6;
  int wm = (wid & 1) * 64;
  int wn = (wid >> 1) * 64;
  int quad = lane >> 4, nib = lane & 15;
  const int lsw = lane ^ ((lane >> 4) << 1);  // swizzled read lane

  f32x4 acc[4][4];
  #pragma unroll
  for (int i = 0; i < 4; ++i)
    #pragma unroll
    for (int j = 0; j < 4; ++j) acc[i][j] = (f32x4){0.f, 0.f, 0.f, 0.f};

  const int rowA = mtile * 128;
  const int rowB = ntile * 128;
  const int c0 = tid, c1 = tid + 256;            // global-order chunks (8 elems)
  // fp32 A base pointers: chunk c covers row c>>2, elems (c&3)*8 .. +8
  const float* pA0 = Af + (size_t)(rowA + (c0 >> 2)) * 1024 + (c0 & 3) * 8;
  const float* pA1 = Af + (size_t)(rowA + (c1 >> 2)) * 1024 + (c1 & 3) * 8;
  const uint4* pB0 = (const uint4*)(BT + (size_t)(rowB + (c0 >> 2)) * 1024 + (c0 & 3) * 8);
  const uint4* pB1 = (const uint4*)(BT + (size_t)(rowB + (c1 >> 2)) * 1024 + (c1 & 3) * 8);
  // bf16 export pointers (ntile==0 blocks only)
  uint16_t* eb0 = encA + (size_t)(rowA + (c0 >> 2)) * 1024 + (c0 & 3) * 8;
  uint16_t* eb1 = encA + (size_t)(rowA + (c1 >> 2)) * 1024 + (c1 & 3) * 8;
  const bool doexp = (ntile == 0);
  // fragment-order LDS slots, XOR-swizzled by kc (kc = c&3, same for c0,c1)
  const int s0 = (((c0 >> 6) << 6) | ((c0 & 3) << 4) | ((c0 >> 2) & 15)) ^ ((c0 & 3) << 1);
  const int s1 = (((c1 >> 6) << 6) | ((c1 & 3) << 4) | ((c1 >> 2) & 15)) ^ ((c1 & 3) << 1);

  // named prefetch sets (NO arrays): set-a = even iters, set-b = odd iters
  float4 A0aL, A0aH, A1aL, A1aH, A0bL, A0bH, A1bL, A1bH;
  uint4 B0a, B1a, B0b, B1b;

#define LDA(L, H, P, K)                                  \
  do {                                                   \
    L = *(const float4*)((P) + (K) * 32);                \
    H = *(const float4*)((P) + (K) * 32 + 4);            \
  } while (0)

  // convert fp32 regs -> packed bf16, ds_write (+export), at stage-iter SK
#define STAGEA(BUF, SK, A0L, A0H, A1L, A1H, B0, B1)                      \
  do {                                                                   \
    uint4 p0, p1;                                                        \
    p0.x = cvtpk(A0L.x, A0L.y); p0.y = cvtpk(A0L.z, A0L.w);              \
    p0.z = cvtpk(A0H.x, A0H.y); p0.w = cvtpk(A0H.z, A0H.w);              \
    p1.x = cvtpk(A1L.x, A1L.y); p1.y = cvtpk(A1L.z, A1L.w);              \
    p1.z = cvtpk(A1H.x, A1H.y); p1.w = cvtpk(A1H.z, A1H.w);              \
    sAB[BUF][s0] = p0; sAB[BUF][s1] = p1;                                \
    sAB[BUF][512 + s0] = B0; sAB[BUF][512 + s1] = B1;                    \
    if (doexp) {                                                         \
      *(uint4*)(eb0 + (SK) * 32) = p0;                                   \
      *(uint4*)(eb1 + (SK) * 32) = p1;                                   \
    }                                                                    \
  } while (0)

#define GEMM_STEP(BUF)                                                          \
  do {                                                                          \
    bf16x8 af[4], bf[4];                                                        \
    _Pragma("unroll")                                                           \
    for (int i = 0; i < 4; ++i)                                                 \
      af[i] = *(const bf16x8*)&sAB[BUF][((wm >> 4) + i) * 64 + lsw];            \
    _Pragma("unroll")                                                           \
    for (int j = 0; j < 4; ++j)                                                 \
      bf[j] = *(const bf16x8*)&sAB[BUF][512 + ((wn >> 4) + j) * 64 + lsw];      \
    _Pragma("unroll")                                                           \
    for (int i = 0; i < 4; ++i)                                                 \
      _Pragma("unroll")                                                         \
      for (int j = 0; j < 4; ++j)                                               \
        acc[i][j] = __builtin_amdgcn_mfma_f32_16x16x32_bf16(af[i], bf[j],       \
                                                            acc[i][j], 0, 0, 0);\
  } while (0)

  // preamble: k=0 -> set-a, k=1 -> set-b; stage k=0 into buf0
  LDA(A0aL, A0aH, pA0, 0); LDA(A1aL, A1aH, pA1, 0);
  B0a = pB0[0]; B1a = pB1[0];
  LDA(A0bL, A0bH, pA0, 1); LDA(A1bL, A1bH, pA1, 1);
  B0b = pB0[4]; B1b = pB1[4];
  STAGEA(0, 0, A0aL, A0aH, A1aL, A1aH, B0a, B1a);
  barrier_lgkm();

  for (int k = 0; k < 32; k += 2) {
    // ---- even body: compute from buf0; set-a free (staged last odd body)
    if (k < 30) {
      LDA(A0aL, A0aH, pA0, k + 2); LDA(A1aL, A1aH, pA1, k + 2);
      B0a = pB0[(k + 2) * 4]; B1a = pB1[(k + 2) * 4];
    }
    GEMM_STEP(0);
    // stage iter k+1 (set-b) into buf1
    STAGEA(1, k + 1, A0bL, A0bH, A1bL, A1bH, B0b, B1b);
    barrier_lgkm();

    // ---- odd body: compute from buf1; set-b free
    if (k < 29) {
      LDA(A0bL, A0bH, pA0, k + 3); LDA(A1bL, A1bH, pA1, k + 3);
      B0b = pB0[(k + 3) * 4]; B1b = pB1[(k + 3) * 4];
    }
    GEMM_STEP(1);
    if (k < 30) {  // stage iter k+2 (set-a) into buf0
      STAGEA(0, k + 2, A0aL, A0aH, A1aL, A1aH, B0a, B1a);
    }
    barrier_lgkm();
  }
#undef GEMM_STEP
#undef STAGEA
#undef LDA

  // ---- epilogue ----
  int b = rowA >> 11;  // 128 | 2048 so batch is block-uniform
  float vv[4], uu[4];
  #pragma unroll
  for (int j = 0; j < 4; ++j) {
    int col = ntile * 128 + wn + j * 16 + nib;
    vv[j] = v[col];
    uu[j] = u[b * 1024 + col];
  }
  float sloc[4][4];
  #pragma unroll
  for (int i = 0; i < 4; ++i) {
    #pragma unroll
    for (int reg = 0; reg < 4; ++reg) {
      float s = 0.f;
      #pragma unroll
      for (int j = 0; j < 4; ++j) s += vv[j] * tanh_fast(acc[i][j][reg] + uu[j]);
      s += __shfl_xor(s, 1);
      s += __shfl_xor(s, 2);
      s += __shfl_xor(s, 4);
      s += __shfl_xor(s, 8);
      sloc[i][reg] = s;  // row = wm + i*16 + quad*4 + reg, cols wn..wn+63
    }
  }
  if (wid < 2 && nib == 0) {  // col-half 0 deposits
    #pragma unroll
    for (int i = 0; i < 4; ++i)
      #pragma unroll
      for (int reg = 0; reg < 4; ++reg)
        sred[wm + i * 16 + quad * 4 + reg] = sloc[i][reg];
  }
  __syncthreads();
  if (wid >= 2 && nib == 0) {  // col-half 1 combines + stores
    float* outp = spart + (size_t)ntile * 65536 + rowA;
    #pragma unroll
    for (int i = 0; i < 4; ++i) {
      int rloc = wm + i * 16 + quad * 4;
      float4 sv;
      #pragma unroll
      for (int reg = 0; reg < 4; ++reg)
        ((float*)&sv)[reg] = sloc[i][reg] + sred[rloc + reg];
      *(float4*)(outp + rloc) = sv;
    }
  }
}

// ---------- 3. softmax over t (2048) per batch; sums the 8 ntile partials ------
__global__ __launch_bounds__(256) void softmax_k(const float* __restrict__ spart,
                                                 float* __restrict__ wout) {
  int b = blockIdx.x, tid = threadIdx.x;
  __shared__ float red[4];
  float sv[8];
  float mx = -1e30f;
  #pragma unroll
  for (int i = 0; i < 8; ++i) {
    int idx = b * 2048 + i * 256 + tid;
    float s = 0.f;
    #pragma unroll
    for (int j = 0; j < 8; ++j) s += spart[j * 65536 + idx];
    sv[i] = s;
    mx = fmaxf(mx, s);
  }
  #pragma unroll
  for (int off = 1; off < 64; off <<= 1) mx = fmaxf(mx, __shfl_xor(mx, off));
  if ((tid & 63) == 0) red[tid >> 6] = mx;
  __syncthreads();
  mx = fmaxf(fmaxf(red[0], red[1]), fmaxf(red[2], red[3]));
  __syncthreads();
  float sum = 0.f;
  #pragma unroll
  for (int i = 0; i < 8; ++i) {
    sv[i] = __expf(sv[i] - mx);
    sum += sv[i];
  }
  #pragma unroll
  for (int off = 1; off < 64; off <<= 1) sum += __shfl_xor(sum, off);
  if ((tid & 63) == 0) red[tid >> 6] = sum;
  __syncthreads();
  float inv = 1.0f / (red[0] + red[1] + red[2] + red[3]);
  #pragma unroll
  for (int i = 0; i < 8; ++i) wout[b * 2048 + i * 256 + tid] = sv[i] * inv;
}

// ---------- 4a. context partials (no atomics): per (b, 128-t chunk) ----------
__global__ __launch_bounds__(256) void context_part(const uint16_t* __restrict__ encA,
                                                    const float* __restrict__ w,
                                                    float* __restrict__ cpart) {
  int b = blockIdx.x >> 4, ch = blockIdx.x & 15;
  int t0 = ch * 128;
  __shared__ float lw[128];
  __shared__ float sctx[1024];
  if (threadIdx.x < 128) lw[threadIdx.x] = w[b * 2048 + t0 + threadIdx.x];
  __syncthreads();
  int th = threadIdx.x >> 7;   // t-half
  int i  = threadIdx.x & 127;  // elem group (8 elems)
  int e0 = i * 8;
  float a[8] = {0.f, 0.f, 0.f, 0.f, 0.f, 0.f, 0.f, 0.f};
  const uint16_t* base = encA + (size_t)b * 2048 * 1024 + (size_t)(t0 + th * 64) * 1024 + e0;
  const float* lwp = lw + th * 64;
  #pragma unroll 2
  for (int t = 0; t < 64; ++t) {
    uint4 p = *(const uint4*)(base + (size_t)t * 1024);
    float wt = lwp[t];
    a[0] = fmaf(wt, b2f_lo(p.x), a[0]);
    a[1] = fmaf(wt, b2f_hi(p.x), a[1]);
    a[2] = fmaf(wt, b2f_lo(p.y), a[2]);
    a[3] = fmaf(wt, b2f_hi(p.y), a[3]);
    a[4] = fmaf(wt, b2f_lo(p.z), a[4]);
    a[5] = fmaf(wt, b2f_hi(p.z), a[5]);
    a[6] = fmaf(wt, b2f_lo(p.w), a[6]);
    a[7] = fmaf(wt, b2f_hi(p.w), a[7]);
  }
  if (th == 0) {
    #pragma unroll
    for (int k = 0; k < 8; ++k) sctx[e0 + k] = a[k];
  }
  __syncthreads();
  if (th == 1) {
    float* cp = cpart + (size_t)(b * 16 + ch) * 1024 + e0;
    float4 v0, v1;
    #pragma unroll
    for (int k = 0; k < 4; ++k) ((float*)&v0)[k] = a[k] + sctx[e0 + k];
    #pragma unroll
    for (int k = 0; k < 4; ++k) ((float*)&v1)[k] = a[4 + k] + sctx[e0 + 4 + k];
    *(float4*)(cp) = v0;
    *(float4*)(cp + 4) = v1;
  }
}

// ---------- 4b. reduce 16 chunk-partials -> ctx (plain stores) ----------
__global__ __launch_bounds__(256) void ctx_reduce(const float* __restrict__ cpart,
                                                  float* __restrict__ ctx) {
  int idx = blockIdx.x * 256 + threadIdx.x;  // 32*1024 outputs
  int b = idx >> 10, e = idx & 1023;
  float s = 0.f;
  #pragma unroll
  for (int r = 0; r < 16; ++r) s += cpart[(size_t)(b * 16 + r) * 1024 + e];
  ctx[idx] = s;
}

extern "C" void kernel_launch(void* const* d_in, const int* in_sizes, int n_in,
                              void* d_out, int out_size, void* d_ws, size_t ws_size,
                              hipStream_t stream) {
  const float* enc = (const float*)d_in[0];  // (32, 2048, 1024)
  const float* dec = (const float*)d_in[1];  // (32, 64, 1024)
  const float* Wa  = (const float*)d_in[2];  // (1024, 1024)
  const float* Ua  = (const float*)d_in[3];  // (1024, 1024)
  const float* Va  = (const float*)d_in[4];  // (1024, 1)

  float* out = (float*)d_out;
  float* ctx = out;                 // 32*1024
  float* wts = out + 32 * 1024;     // 32*2048*1

  char* ws = (char*)d_ws;
  uint16_t* encA  = (uint16_t*)ws;                           // 128 MB bf16 encoder (gemm side-output)
  uint16_t* WT    = (uint16_t*)(ws + 134217728);             // 2 MB bf16 W^T
  float*    ub    = (float*)  (ws + 136314880);              // 128 KB u[b,f]
  float*    spart = (float*)  (ws + 136445952);              // 2 MB score partials [8][65536]
  float*    cpart = spart;  // context partials [512][1024] reuse spart (dead after softmax)

  hipMemsetAsync(ub, 0, 32 * 1024 * sizeof(float), stream);

  prep<<<512, 256, 0, stream>>>(Wa, WT, dec, (const float4*)Ua, ub);
  gemm_score<<<4096, 256, 0, stream>>>(enc, WT, ub, Va, spart, encA);
  softmax_k<<<32, 256, 0, stream>>>(spart, wts);
  context_part<<<512, 256, 0, stream>>>(encA, wts, cpart);
  ctx_reduce<<<128, 256, 0, stream>>>(cpart, ctx);
}

// Round 5
// 616.714 us; speedup vs baseline: 1.1811x; 1.1811x over previous
//
#include <hip/hip_runtime.h>
#include <stdint.h>

typedef __attribute__((ext_vector_type(8))) __bf16 bf16x8;
typedef __attribute__((ext_vector_type(4))) float  f32x4;

// ---------- helpers ----------
__device__ __forceinline__ uint16_t f2b(float f) {           // fp32 -> bf16 RNE
  uint32_t u = __float_as_uint(f);
  u += 0x7fffu + ((u >> 16) & 1u);
  return (uint16_t)(u >> 16);
}

// hardware packed fp32->bf16 RNE (2 elems / instr); same rounding as f2b
__device__ __forceinline__ uint32_t cvtpk(float lo, float hi) {
  uint32_t r;
  asm("v_cvt_pk_bf16_f32 %0, %1, %2" : "=v"(r) : "v"(lo), "v"(hi));
  return r;
}

// branch-free tanh: 1 - 2/(e^{2x}+1); saturates correctly at +-1
__device__ __forceinline__ float tanh_fast(float x) {
  float e = __expf(2.0f * x);
  return 1.0f - 2.0f / (e + 1.0f);
}

// barrier draining ONLY lgkmcnt (ds ops) — global prefetch stays in flight.
__device__ __forceinline__ void barrier_lgkm() {
  asm volatile("s_waitcnt lgkmcnt(0)\n\ts_barrier" ::: "memory");
}

// ---------- 1. prep: W_a transpose->bf16 (blocks 0..255) + u = dec_last @ U_a
//              (blocks 256..511, atomic fp32 partials) merged into one dispatch.
__global__ __launch_bounds__(256) void prep(const float* __restrict__ W,
                                            uint16_t* __restrict__ WT,
                                            const float* __restrict__ dec,
                                            const float4* __restrict__ U4,
                                            float* __restrict__ u) {
  __shared__ float tile[64][65];
  if (blockIdx.x < 256) {
    // ---- W_a (K x N) -> WT bf16 (N x K), LDS-tiled transpose ----
    int k0 = (blockIdx.x & 15) * 64;
    int n0 = (blockIdx.x >> 4) * 64;
    #pragma unroll
    for (int it = 0; it < 16; ++it) {
      int idx = it * 256 + threadIdx.x;
      int kr = idx >> 6, nc = idx & 63;
      tile[kr][nc] = W[(size_t)(k0 + kr) * 1024 + n0 + nc];
    }
    __syncthreads();
    #pragma unroll
    for (int it = 0; it < 16; ++it) {
      int idx = it * 256 + threadIdx.x;
      int nr = idx >> 6, kc = idx & 63;
      WT[(size_t)(n0 + nr) * 1024 + k0 + kc] = f2b(tile[kc][nr]);
    }
  } else {
    // ---- u[b,f] += sum_{d in seg} dec_last[b,d] * U[d,f] ----
    int bx = blockIdx.x - 256;
    int b = bx >> 3, dseg = bx & 7;
    float* sdec = &tile[0][0];
    if (threadIdx.x < 128)
      sdec[threadIdx.x] = dec[(size_t)b * 64 * 1024 + 63 * 1024 + dseg * 128 + threadIdx.x];
    __syncthreads();
    float4 a = {0.f, 0.f, 0.f, 0.f};
    const float4* Ub = U4 + (size_t)dseg * 128 * 256 + threadIdx.x;
    #pragma unroll 4
    for (int d = 0; d < 128; ++d) {
      float4 w = Ub[(size_t)d * 256];
      float s = sdec[d];
      a.x = fmaf(s, w.x, a.x);
      a.y = fmaf(s, w.y, a.y);
      a.z = fmaf(s, w.z, a.z);
      a.w = fmaf(s, w.w, a.w);
    }
    float* up = u + b * 1024 + threadIdx.x * 4;
    atomicAdd(up + 0, a.x);
    atomicAdd(up + 1, a.y);
    atomicAdd(up + 2, a.z);
    atomicAdd(up + 3, a.w);
  }
}

// ---------- 2. fused GEMM (R0 structure), fp32 A staged via in-reg bf16 convert
// spart[ntile][r] = sum_{f in ntile} v[f]*tanh((A@W)[r,f]+u[b,f])
// 128x128 tile, 4 waves, BK=32, LDS double-buffer, lgkm-only barrier, named
// prefetch regs, XOR-swizzled fragment-order LDS slots (proven: 0 conflicts).
// A loaded as fp32 (2x float4 per 16B-bf16 chunk), packed via
// v_cvt_pk_bf16_f32 at ds_write time. NO encA export (R4 lesson: scattered
// 64B-granularity global writes from the staging path caused 3x write
// amplification, 385 MB -> kernel went HBM-bound at 1.4 TB/s).
__global__ __launch_bounds__(256, 3) void gemm_score(const float* __restrict__ Af,
                                                     const uint16_t* __restrict__ BT,
                                                     const float* __restrict__ u,
                                                     const float* __restrict__ v,
                                                     float* __restrict__ spart) {
  __shared__ uint4 sAB[2][1024];  // [buf][ A slots 0..511 | B slots 512..1023 ]
  __shared__ float sred[128];

  int bx = blockIdx.x;
  int g = bx >> 6, r = bx & 63;
  int mtile = g * 8 + (r & 7);
  int ntile = r >> 3;

  int tid = threadIdx.x;
  int lane = tid & 63;
  int wid  = tid >> 6;
  int wm = (wid & 1) * 64;
  int wn = (wid >> 1) * 64;
  int quad = lane >> 4, nib = lane & 15;
  const int lsw = lane ^ ((lane >> 4) << 1);  // swizzled read lane

  f32x4 acc[4][4];
  #pragma unroll
  for (int i = 0; i < 4; ++i)
    #pragma unroll
    for (int j = 0; j < 4; ++j) acc[i][j] = (f32x4){0.f, 0.f, 0.f, 0.f};

  const int rowA = mtile * 128;
  const int rowB = ntile * 128;
  const int c0 = tid, c1 = tid + 256;            // global-order chunks (8 elems)
  // fp32 A base pointers: chunk c covers row c>>2, elems (c&3)*8 .. +8
  const float* pA0 = Af + (size_t)(rowA + (c0 >> 2)) * 1024 + (c0 & 3) * 8;
  const float* pA1 = Af + (size_t)(rowA + (c1 >> 2)) * 1024 + (c1 & 3) * 8;
  const uint4* pB0 = (const uint4*)(BT + (size_t)(rowB + (c0 >> 2)) * 1024 + (c0 & 3) * 8);
  const uint4* pB1 = (const uint4*)(BT + (size_t)(rowB + (c1 >> 2)) * 1024 + (c1 & 3) * 8);
  // fragment-order LDS slots, XOR-swizzled by kc (kc = c&3, same for c0,c1)
  const int s0 = (((c0 >> 6) << 6) | ((c0 & 3) << 4) | ((c0 >> 2) & 15)) ^ ((c0 & 3) << 1);
  const int s1 = (((c1 >> 6) << 6) | ((c1 & 3) << 4) | ((c1 >> 2) & 15)) ^ ((c1 & 3) << 1);

  // named prefetch sets (NO arrays): set-a = even iters, set-b = odd iters
  float4 A0aL, A0aH, A1aL, A1aH, A0bL, A0bH, A1bL, A1bH;
  uint4 B0a, B1a, B0b, B1b;

#define LDA(L, H, P, K)                                  \
  do {                                                   \
    L = *(const float4*)((P) + (K) * 32);                \
    H = *(const float4*)((P) + (K) * 32 + 4);            \
  } while (0)

  // convert fp32 regs -> packed bf16, ds_write
#define STAGEA(BUF, A0L, A0H, A1L, A1H, B0, B1)                          \
  do {                                                                   \
    uint4 p0, p1;                                                        \
    p0.x = cvtpk(A0L.x, A0L.y); p0.y = cvtpk(A0L.z, A0L.w);              \
    p0.z = cvtpk(A0H.x, A0H.y); p0.w = cvtpk(A0H.z, A0H.w);              \
    p1.x = cvtpk(A1L.x, A1L.y); p1.y = cvtpk(A1L.z, A1L.w);              \
    p1.z = cvtpk(A1H.x, A1H.y); p1.w = cvtpk(A1H.z, A1H.w);              \
    sAB[BUF][s0] = p0; sAB[BUF][s1] = p1;                                \
    sAB[BUF][512 + s0] = B0; sAB[BUF][512 + s1] = B1;                    \
  } while (0)

#define GEMM_STEP(BUF)                                                          \
  do {                                                                          \
    bf16x8 af[4], bf[4];                                                        \
    _Pragma("unroll")                                                           \
    for (int i = 0; i < 4; ++i)                                                 \
      af[i] = *(const bf16x8*)&sAB[BUF][((wm >> 4) + i) * 64 + lsw];            \
    _Pragma("unroll")                                                           \
    for (int j = 0; j < 4; ++j)                                                 \
      bf[j] = *(const bf16x8*)&sAB[BUF][512 + ((wn >> 4) + j) * 64 + lsw];      \
    _Pragma("unroll")                                                           \
    for (int i = 0; i < 4; ++i)                                                 \
      _Pragma("unroll")                                                         \
      for (int j = 0; j < 4; ++j)                                               \
        acc[i][j] = __builtin_amdgcn_mfma_f32_16x16x32_bf16(af[i], bf[j],       \
                                                            acc[i][j], 0, 0, 0);\
  } while (0)

  // preamble: k=0 -> set-a, k=1 -> set-b; stage k=0 into buf0
  LDA(A0aL, A0aH, pA0, 0); LDA(A1aL, A1aH, pA1, 0);
  B0a = pB0[0]; B1a = pB1[0];
  LDA(A0bL, A0bH, pA0, 1); LDA(A1bL, A1bH, pA1, 1);
  B0b = pB0[4]; B1b = pB1[4];
  STAGEA(0, A0aL, A0aH, A1aL, A1aH, B0a, B1a);
  barrier_lgkm();

  for (int k = 0; k < 32; k += 2) {
    // ---- even body: compute from buf0; set-a free (staged last odd body)
    if (k < 30) {
      LDA(A0aL, A0aH, pA0, k + 2); LDA(A1aL, A1aH, pA1, k + 2);
      B0a = pB0[(k + 2) * 4]; B1a = pB1[(k + 2) * 4];
    }
    GEMM_STEP(0);
    // stage iter k+1 (set-b) into buf1
    STAGEA(1, A0bL, A0bH, A1bL, A1bH, B0b, B1b);
    barrier_lgkm();

    // ---- odd body: compute from buf1; set-b free
    if (k < 29) {
      LDA(A0bL, A0bH, pA0, k + 3); LDA(A1bL, A1bH, pA1, k + 3);
      B0b = pB0[(k + 3) * 4]; B1b = pB1[(k + 3) * 4];
    }
    GEMM_STEP(1);
    if (k < 30) {  // stage iter k+2 (set-a) into buf0
      STAGEA(0, A0aL, A0aH, A1aL, A1aH, B0a, B1a);
    }
    barrier_lgkm();
  }
#undef GEMM_STEP
#undef STAGEA
#undef LDA

  // ---- epilogue ----
  int b = rowA >> 11;  // 128 | 2048 so batch is block-uniform
  float vv[4], uu[4];
  #pragma unroll
  for (int j = 0; j < 4; ++j) {
    int col = ntile * 128 + wn + j * 16 + nib;
    vv[j] = v[col];
    uu[j] = u[b * 1024 + col];
  }
  float sloc[4][4];
  #pragma unroll
  for (int i = 0; i < 4; ++i) {
    #pragma unroll
    for (int reg = 0; reg < 4; ++reg) {
      float s = 0.f;
      #pragma unroll
      for (int j = 0; j < 4; ++j) s += vv[j] * tanh_fast(acc[i][j][reg] + uu[j]);
      s += __shfl_xor(s, 1);
      s += __shfl_xor(s, 2);
      s += __shfl_xor(s, 4);
      s += __shfl_xor(s, 8);
      sloc[i][reg] = s;  // row = wm + i*16 + quad*4 + reg, cols wn..wn+63
    }
  }
  if (wid < 2 && nib == 0) {  // col-half 0 deposits
    #pragma unroll
    for (int i = 0; i < 4; ++i)
      #pragma unroll
      for (int reg = 0; reg < 4; ++reg)
        sred[wm + i * 16 + quad * 4 + reg] = sloc[i][reg];
  }
  __syncthreads();
  if (wid >= 2 && nib == 0) {  // col-half 1 combines + stores
    float* outp = spart + (size_t)ntile * 65536 + rowA;
    #pragma unroll
    for (int i = 0; i < 4; ++i) {
      int rloc = wm + i * 16 + quad * 4;
      float4 sv;
      #pragma unroll
      for (int reg = 0; reg < 4; ++reg)
        ((float*)&sv)[reg] = sloc[i][reg] + sred[rloc + reg];
      *(float4*)(outp + rloc) = sv;
    }
  }
}

// ---------- 3. softmax over t (2048) per batch; sums the 8 ntile partials ------
__global__ __launch_bounds__(256) void softmax_k(const float* __restrict__ spart,
                                                 float* __restrict__ wout) {
  int b = blockIdx.x, tid = threadIdx.x;
  __shared__ float red[4];
  float sv[8];
  float mx = -1e30f;
  #pragma unroll
  for (int i = 0; i < 8; ++i) {
    int idx = b * 2048 + i * 256 + tid;
    float s = 0.f;
    #pragma unroll
    for (int j = 0; j < 8; ++j) s += spart[j * 65536 + idx];
    sv[i] = s;
    mx = fmaxf(mx, s);
  }
  #pragma unroll
  for (int off = 1; off < 64; off <<= 1) mx = fmaxf(mx, __shfl_xor(mx, off));
  if ((tid & 63) == 0) red[tid >> 6] = mx;
  __syncthreads();
  mx = fmaxf(fmaxf(red[0], red[1]), fmaxf(red[2], red[3]));
  __syncthreads();
  float sum = 0.f;
  #pragma unroll
  for (int i = 0; i < 8; ++i) {
    sv[i] = __expf(sv[i] - mx);
    sum += sv[i];
  }
  #pragma unroll
  for (int off = 1; off < 64; off <<= 1) sum += __shfl_xor(sum, off);
  if ((tid & 63) == 0) red[tid >> 6] = sum;
  __syncthreads();
  float inv = 1.0f / (red[0] + red[1] + red[2] + red[3]);
  #pragma unroll
  for (int i = 0; i < 8; ++i) wout[b * 2048 + i * 256 + tid] = sv[i] * inv;
}

// ---------- 4a. context partials (no atomics), fp32 enc: per (b, 128-t chunk) --
__global__ __launch_bounds__(256) void context_part(const float* __restrict__ enc,
                                                    const float* __restrict__ w,
                                                    float* __restrict__ cpart) {
  int b = blockIdx.x >> 4, ch = blockIdx.x & 15;
  int t0 = ch * 128;
  __shared__ float lw[128];
  __shared__ float sctx[1024];
  if (threadIdx.x < 128) lw[threadIdx.x] = w[b * 2048 + t0 + threadIdx.x];
  __syncthreads();
  int th = threadIdx.x >> 7;   // t-half
  int i  = threadIdx.x & 127;  // elem group (8 elems)
  int e0 = i * 8;
  float a[8] = {0.f, 0.f, 0.f, 0.f, 0.f, 0.f, 0.f, 0.f};
  const float* base = enc + (size_t)b * 2048 * 1024 + (size_t)(t0 + th * 64) * 1024 + e0;
  const float* lwp = lw + th * 64;
  #pragma unroll 2
  for (int t = 0; t < 64; ++t) {
    float4 p0 = *(const float4*)(base + (size_t)t * 1024);
    float4 p1 = *(const float4*)(base + (size_t)t * 1024 + 4);
    float wt = lwp[t];
    a[0] = fmaf(wt, p0.x, a[0]);
    a[1] = fmaf(wt, p0.y, a[1]);
    a[2] = fmaf(wt, p0.z, a[2]);
    a[3] = fmaf(wt, p0.w, a[3]);
    a[4] = fmaf(wt, p1.x, a[4]);
    a[5] = fmaf(wt, p1.y, a[5]);
    a[6] = fmaf(wt, p1.z, a[6]);
    a[7] = fmaf(wt, p1.w, a[7]);
  }
  if (th == 0) {
    #pragma unroll
    for (int k = 0; k < 8; ++k) sctx[e0 + k] = a[k];
  }
  __syncthreads();
  if (th == 1) {
    float* cp = cpart + (size_t)(b * 16 + ch) * 1024 + e0;
    float4 v0, v1;
    #pragma unroll
    for (int k = 0; k < 4; ++k) ((float*)&v0)[k] = a[k] + sctx[e0 + k];
    #pragma unroll
    for (int k = 0; k < 4; ++k) ((float*)&v1)[k] = a[4 + k] + sctx[e0 + 4 + k];
    *(float4*)(cp) = v0;
    *(float4*)(cp + 4) = v1;
  }
}

// ---------- 4b. reduce 16 chunk-partials -> ctx (plain stores) ----------
__global__ __launch_bounds__(256) void ctx_reduce(const float* __restrict__ cpart,
                                                  float* __restrict__ ctx) {
  int idx = blockIdx.x * 256 + threadIdx.x;  // 32*1024 outputs
  int b = idx >> 10, e = idx & 1023;
  float s = 0.f;
  #pragma unroll
  for (int r = 0; r < 16; ++r) s += cpart[(size_t)(b * 16 + r) * 1024 + e];
  ctx[idx] = s;
}

extern "C" void kernel_launch(void* const* d_in, const int* in_sizes, int n_in,
                              void* d_out, int out_size, void* d_ws, size_t ws_size,
                              hipStream_t stream) {
  const float* enc = (const float*)d_in[0];  // (32, 2048, 1024)
  const float* dec = (const float*)d_in[1];  // (32, 64, 1024)
  const float* Wa  = (const float*)d_in[2];  // (1024, 1024)
  const float* Ua  = (const float*)d_in[3];  // (1024, 1024)
  const float* Va  = (const float*)d_in[4];  // (1024, 1)

  float* out = (float*)d_out;
  float* ctx = out;                 // 32*1024
  float* wts = out + 32 * 1024;     // 32*2048*1

  char* ws = (char*)d_ws;
  uint16_t* WT    = (uint16_t*)ws;                           // 2 MB bf16 W^T
  float*    ub    = (float*)  (ws + 2097152);                // 128 KB u[b,f]
  float*    spart = (float*)  (ws + 2228224);                // 2 MB score partials [8][65536]
  float*    cpart = spart;  // context partials [512][1024] reuse spart (dead after softmax)

  hipMemsetAsync(ub, 0, 32 * 1024 * sizeof(float), stream);

  prep<<<512, 256, 0, stream>>>(Wa, WT, dec, (const float4*)Ua, ub);
  gemm_score<<<4096, 256, 0, stream>>>(enc, WT, ub, Va, spart);
  softmax_k<<<32, 256, 0, stream>>>(spart, wts);
  context_part<<<512, 256, 0, stream>>>(enc, wts, cpart);
  ctx_reduce<<<128, 256, 0, stream>>>(cpart, ctx);
}